// Round 9
// baseline (226.857 us; speedup 1.0000x reference)
//
#include <hip/hip_runtime.h>

#define NN 100000
#define DD 128
#define HH 256
#define NE 600000
#define CAP 32   // max in-degree bucket capacity; Poisson(mean 6) => P(>=32) ~ 4e-16

typedef short bf8 __attribute__((ext_vector_type(8)));       // 8 bf16 (4 VGPRs)
typedef float f32x4 __attribute__((ext_vector_type(4)));     // MFMA C/D
typedef float f32x2 __attribute__((ext_vector_type(2)));
typedef unsigned short u16x8 __attribute__((ext_vector_type(8)));
typedef int i32x4 __attribute__((ext_vector_type(4)));

__device__ __forceinline__ unsigned short f2bf(float f) {
  unsigned int u = __builtin_bit_cast(unsigned int, f);
  u += 0x7fffu + ((u >> 16) & 1u);          // RNE
  return (unsigned short)(u >> 16);
}
__device__ __forceinline__ float bf2f(unsigned short h) {
  unsigned int u = ((unsigned int)h) << 16;
  return __builtin_bit_cast(float, u);
}

// ---- prep (2048 blocks): edge-bucket fill (moved here from msg_mlp — its
// atomic latency + 35MB of scattered-store writeback hide under this kernel's
// streaming BW headroom) + nodes->bf16 Xb + Mb zero-row + weight pack.
// Requires (stream-ordered) hipMemsetAsync before launch: cnt=0 and
// ebuf=0x01010101 sentinel (>NN; gather min-clamps slots to the zero row).
__global__ __launch_bounds__(256) void prep(
    const float* __restrict__ Wm1, const float* __restrict__ Wm2,
    const float* __restrict__ Wn1, const float* __restrict__ Wn2,
    unsigned short* __restrict__ Pm1, unsigned short* __restrict__ Pm2,
    unsigned short* __restrict__ Pn1, unsigned short* __restrict__ Pn2,
    int* __restrict__ cnt,
    const float* __restrict__ nodes, unsigned short* __restrict__ Xb,
    unsigned char* __restrict__ Mb,
    const int* __restrict__ snd, const int* __restrict__ rcv,
    int* __restrict__ ebuf) {
  int b = blockIdx.x;
  int gid = b * 256 + threadIdx.x;

  // edge fill at HEAD: atomic round-trips overlap the streaming loops below
  for (int e = gid; e < NE; e += 2048 * 256) {
    int r = rcv[e];
    int pos = atomicAdd(&cnt[r], 1);
    if (pos < CAP) ebuf[r * CAP + pos] = snd[e];
  }

  // zero-row Mb[NN] (fp8 0x00 == 0.0f; sentinel slots land here)
  if (b == 0 && threadIdx.x < 8)
    ((i32x4*)(Mb + (size_t)NN * DD))[threadIdx.x] = (i32x4){0, 0, 0, 0};

  // nodes fp32 -> Xb bf16 (8 elems per iter)
  for (int i = gid; i < NN * DD / 8; i += 2048 * 256) {
    const float4 v0 = ((const float4*)nodes)[i * 2];
    const float4 v1 = ((const float4*)nodes)[i * 2 + 1];
    u16x8 o;
    o[0] = f2bf(v0.x); o[1] = f2bf(v0.y); o[2] = f2bf(v0.z); o[3] = f2bf(v0.w);
    o[4] = f2bf(v1.x); o[5] = f2bf(v1.y); o[6] = f2bf(v1.z); o[7] = f2bf(v1.w);
    ((u16x8*)Xb)[i] = o;
  }

  // weight packing on blocks 0..79
  // P[((nt*(K/32)+kt)*64 + lane)*8 + j] = W[kt*32+(lane>>4)*8+j][nt*16+(lane&15)]
  if (b < 80) {
    const float* W; unsigned short* P; int K, N, base;
    if (b < 16)      { W = Wm1; P = Pm1; K = 128; N = 256; base = 0;  }
    else if (b < 32) { W = Wm2; P = Pm2; K = 256; N = 128; base = 16; }
    else if (b < 64) { W = Wn1; P = Pn1; K = 256; N = 256; base = 32; }
    else             { W = Wn2; P = Pn2; K = 256; N = 128; base = 64; }
    int idx = (b - base) * 256 + threadIdx.x;
    int KT = K >> 5;
    int lane = idx & 63;
    int t = idx >> 6;
    int kt = t % KT, nt = t / KT;
    int n = nt * 16 + (lane & 15);
    int k0 = kt * 32 + (lane >> 4) * 8;
    unsigned short* dst = P + (size_t)idx * 8;
#pragma unroll
    for (int j = 0; j < 8; ++j) dst[j] = f2bf(W[(size_t)(k0 + j) * N + n]);
  }
}

// ---- message MLP: 512 thr / 8 waves / 64-row tile. Now PURE MFMA pipeline:
// stage -> L1 -> epi1 -> L2 -> fp8 store. No atomics, no scatter (moved to prep).
__global__ __launch_bounds__(512) void msg_mlp(
    const unsigned short* __restrict__ Xb,
    const unsigned short* __restrict__ W1p, const float* __restrict__ b1,
    const unsigned short* __restrict__ W2p, const float* __restrict__ b2,
    unsigned char* __restrict__ Mb) {
  __shared__ __align__(16) unsigned short h[64][264];
  const int row0 = blockIdx.x * 64;
  const int tid = threadIdx.x;
  const int lane = tid & 63, wave = tid >> 6;   // 0..7
  const int l15 = lane & 15, l4 = lane >> 4;

  // stage X tile (64x128 bf16) from warm Xb
#pragma unroll
  for (int i = 0; i < 2; ++i) {
    int flat = (i * 512 + tid) * 8;
    int r = flat >> 7, c = flat & 127;
    u16x8 v = (u16x8)0;
    if (row0 + r < NN) v = *(const u16x8*)(Xb + (size_t)(row0 + r) * DD + c);
    *(u16x8*)&h[r][c] = v;
  }
  __syncthreads();

  // layer 1 (transposed): D[H=256][node=64], K=128. Wave owns 32 H rows.
  f32x4 acc[2][4];
#pragma unroll
  for (int mt = 0; mt < 2; ++mt)
#pragma unroll
    for (int nt = 0; nt < 4; ++nt) acc[mt][nt] = (f32x4){0.f, 0.f, 0.f, 0.f};
#pragma unroll
  for (int kt = 0; kt < 4; ++kt) {
    bf8 wfr[2], xfr[4];
#pragma unroll
    for (int mt = 0; mt < 2; ++mt) {
      int Htile = wave * 2 + mt;
      wfr[mt] = *(const bf8*)(W1p + ((size_t)(Htile * 4 + kt) * 64 + lane) * 8);
    }
#pragma unroll
    for (int nt = 0; nt < 4; ++nt)
      xfr[nt] = *(const bf8*)&h[nt * 16 + l15][kt * 32 + l4 * 8];
#pragma unroll
    for (int mt = 0; mt < 2; ++mt)
#pragma unroll
      for (int nt = 0; nt < 4; ++nt)
        acc[mt][nt] = __builtin_amdgcn_mfma_f32_16x16x32_bf16(wfr[mt], xfr[nt], acc[mt][nt], 0, 0, 0);
  }
  __syncthreads();

  // epilogue 1: bias + relu, vectorized writes h[node][H]
#pragma unroll
  for (int mt = 0; mt < 2; ++mt) {
    int Hbase = wave * 32 + mt * 16 + l4 * 4;
    float4 bv = *(const float4*)(b1 + Hbase);
#pragma unroll
    for (int nt = 0; nt < 4; ++nt) {
      ushort4 o;
      float v0 = acc[mt][nt][0] + bv.x; o.x = f2bf(v0 > 0.f ? v0 : 0.f);
      float v1 = acc[mt][nt][1] + bv.y; o.y = f2bf(v1 > 0.f ? v1 : 0.f);
      float v2 = acc[mt][nt][2] + bv.z; o.z = f2bf(v2 > 0.f ? v2 : 0.f);
      float v3 = acc[mt][nt][3] + bv.w; o.w = f2bf(v3 > 0.f ? v3 : 0.f);
      *(ushort4*)&h[nt * 16 + l15][Hbase] = o;
    }
  }
  __syncthreads();

  // layer 2 (transposed): D[Dout=128][node=64], K=256. Wave owns 16 Dout rows.
  f32x4 acc2[4];
#pragma unroll
  for (int nt = 0; nt < 4; ++nt) acc2[nt] = (f32x4){0.f, 0.f, 0.f, 0.f};
#pragma unroll
  for (int kt = 0; kt < 8; ++kt) {
    bf8 wfr, xfr[4];
    wfr = *(const bf8*)(W2p + ((size_t)(wave * 8 + kt) * 64 + lane) * 8);
#pragma unroll
    for (int nt = 0; nt < 4; ++nt)
      xfr[nt] = *(const bf8*)&h[nt * 16 + l15][kt * 32 + l4 * 8];
#pragma unroll
    for (int nt = 0; nt < 4; ++nt)
      acc2[nt] = __builtin_amdgcn_mfma_f32_16x16x32_bf16(wfr, xfr[nt], acc2[nt], 0, 0, 0);
  }
  // epilogue 2: bias + store Mb fp8 (HW RNE convert, 4B/lane)
  {
    int Dbase = wave * 16 + l4 * 4;
    float4 bv = *(const float4*)(b2 + Dbase);
#pragma unroll
    for (int nt = 0; nt < 4; ++nt) {
      int node = row0 + nt * 16 + l15;
      if (node < NN) {
        int p = 0;
        p = __builtin_amdgcn_cvt_pk_fp8_f32(acc2[nt][0] + bv.x, acc2[nt][1] + bv.y, p, false);
        p = __builtin_amdgcn_cvt_pk_fp8_f32(acc2[nt][2] + bv.z, acc2[nt][3] + bv.w, p, true);
        *(unsigned int*)(Mb + (size_t)node * DD + Dbase) = (unsigned int)p;
      }
    }
  }
}

// ---- node MLP fused with gather: 256 thr / 4 waves / 32-row tile (grid 3125).
// Straight-line gather (r8 structure); slots min-clamped to NN (sentinel
// 0x01010101 from the ebuf memset > NN -> zero row; 1 v_min_u32 per slot,
// still branch-free/mask-free). NT loads on single-use streams; NORMAL out
// stores (r7: NT stores cost +21MB WRITE).
__global__ __launch_bounds__(256) void node_fused(
    const unsigned short* __restrict__ Xb, const unsigned char* __restrict__ Mb,
    const int* __restrict__ ebuf, const int* __restrict__ cnt,
    const unsigned short* __restrict__ W1p, const float* __restrict__ b1,
    const unsigned short* __restrict__ W2p, const float* __restrict__ b2,
    float* __restrict__ out) {
  __shared__ __align__(16) unsigned short h[32][264];
  const int row0 = blockIdx.x * 32;
  const int tid = threadIdx.x;
  const int lane = tid & 63, wave = tid >> 6;   // 0..3
  const int l15 = lane & 15, l4 = lane >> 4;
  const int halfid = lane >> 5, sub = lane & 31;

  // degrees (half-wave per node: 8 half-waves x 4 rounds = 32 nodes)
  int degv[4];
#pragma unroll
  for (int t = 0; t < 4; ++t) {
    int node = row0 + t * 8 + wave * 2 + halfid;
    int d = cnt[node];
    degv[t] = d < CAP ? d : CAP;
  }

  // stage ebuf slot tile (32 nodes x 32 slots = 4KB) into agg region of h.
  // Slots stay valid until the deferred agg-write phase (after tails).
  {
    int idx = tid * 4;                      // 1024 ints total
    int r = idx >> 5, s = idx & 31;
    i32x4 v = __builtin_nontemporal_load((const i32x4*)(ebuf + (size_t)row0 * CAP + idx));
    *(i32x4*)(((int*)&h[r][128]) + s) = v;
  }

  // stage X tile (32x128 bf16) from Xb, cols 0..127 (read-once: nt)
#pragma unroll
  for (int i = 0; i < 2; ++i) {
    int flat = (i * 256 + tid) * 8;
    int r = flat >> 7, c = flat & 127;
    u16x8 v = __builtin_nontemporal_load((const u16x8*)(Xb + (size_t)(row0 + r) * DD + c));
    *(u16x8*)&h[r][c] = v;
  }
  __syncthreads();

  // ---- gather main phase: 4 rounds, branch-free, mask-free, no LDS writes ----
  ushort4 oreg[4];
#pragma unroll
  for (int t = 0; t < 4; ++t) {
    int ln = t * 8 + wave * 2 + halfid;
    const int* sl_p = (const int*)&h[ln][128];   // broadcast reads (same addr)
    unsigned int mv[8];
#pragma unroll
    for (int u = 0; u < 8; ++u) {
      unsigned int se = (unsigned int)sl_p[u];
      se = se < NN ? se : NN;                    // sentinel -> zero row (v_min)
      mv[u] = *(const unsigned int*)(Mb + (size_t)se * DD + sub * 4);
    }
    float a0 = 0.f, a1 = 0.f, a2 = 0.f, a3 = 0.f;
#pragma unroll
    for (int u = 0; u < 8; ++u) {
      f32x2 lo = __builtin_amdgcn_cvt_pk_f32_fp8((int)mv[u], false);
      f32x2 hi = __builtin_amdgcn_cvt_pk_f32_fp8((int)mv[u], true);
      a0 += lo[0]; a1 += lo[1]; a2 += hi[0]; a3 += hi[1];
    }
    ushort4 o;
    o.x = f2bf(a0); o.y = f2bf(a1); o.z = f2bf(a2); o.w = f2bf(a3);
    oreg[t] = o;
  }

  // ---- tails (deg > 8, rare): unpack partial, add, repack ----
#pragma unroll
  for (int t = 0; t < 4; ++t) {
    int deg = degv[t];
    if (deg > 8) {
      int ln = t * 8 + wave * 2 + halfid;
      const int* sl_p = (const int*)&h[ln][128];
      float a0 = bf2f(oreg[t].x), a1 = bf2f(oreg[t].y);
      float a2 = bf2f(oreg[t].z), a3 = bf2f(oreg[t].w);
      for (int bb = 8; bb < deg; bb += 8) {
        unsigned int mv[8];
#pragma unroll
        for (int u = 0; u < 8; ++u) {
          unsigned int se = (unsigned int)sl_p[bb + u];
          se = se < NN ? se : NN;
          mv[u] = *(const unsigned int*)(Mb + (size_t)se * DD + sub * 4);
        }
#pragma unroll
        for (int u = 0; u < 8; ++u) {
          f32x2 lo = __builtin_amdgcn_cvt_pk_f32_fp8((int)mv[u], false);
          f32x2 hi = __builtin_amdgcn_cvt_pk_f32_fp8((int)mv[u], true);
          a0 += lo[0]; a1 += lo[1]; a2 += hi[0]; a3 += hi[1];
        }
      }
      ushort4 o;
      o.x = f2bf(a0); o.y = f2bf(a1); o.z = f2bf(a2); o.w = f2bf(a3);
      oreg[t] = o;
    }
  }

  // ---- single agg write phase (slots consumed; each half owns its rows) ----
#pragma unroll
  for (int t = 0; t < 4; ++t) {
    int ln = t * 8 + wave * 2 + halfid;
    *(ushort4*)&h[ln][128 + sub * 4] = oreg[t];
  }
  __syncthreads();

  // residual snapshot (bf16, before epilogue-1 overwrites h cols 0..127)
  ushort4 resid[2][2];
#pragma unroll
  for (int mt = 0; mt < 2; ++mt)
#pragma unroll
    for (int nt = 0; nt < 2; ++nt)
      resid[mt][nt] = *(ushort4*)&h[nt * 16 + l15][(wave * 2 + mt) * 16 + l4 * 4];

  // layer 1 (transposed): D[H=256][node=32], K=256. Wave owns 64 H rows (4 tiles).
  f32x4 acc[4][2];
#pragma unroll
  for (int mt = 0; mt < 4; ++mt)
#pragma unroll
    for (int nt = 0; nt < 2; ++nt) acc[mt][nt] = (f32x4){0.f, 0.f, 0.f, 0.f};
#pragma unroll
  for (int kt = 0; kt < 8; ++kt) {
    bf8 wfr[4], xfr[2];
#pragma unroll
    for (int mt = 0; mt < 4; ++mt) {
      int Htile = wave * 4 + mt;
      wfr[mt] = *(const bf8*)(W1p + ((size_t)(Htile * 8 + kt) * 64 + lane) * 8);
    }
#pragma unroll
    for (int nt = 0; nt < 2; ++nt)
      xfr[nt] = *(const bf8*)&h[nt * 16 + l15][kt * 32 + l4 * 8];
#pragma unroll
    for (int mt = 0; mt < 4; ++mt)
#pragma unroll
      for (int nt = 0; nt < 2; ++nt)
        acc[mt][nt] = __builtin_amdgcn_mfma_f32_16x16x32_bf16(wfr[mt], xfr[nt], acc[mt][nt], 0, 0, 0);
  }
  __syncthreads();

  // epilogue 1: bias + relu
#pragma unroll
  for (int mt = 0; mt < 4; ++mt) {
    int Hbase = (wave * 4 + mt) * 16 + l4 * 4;
    float4 bv = *(const float4*)(b1 + Hbase);
#pragma unroll
    for (int nt = 0; nt < 2; ++nt) {
      ushort4 o;
      float v0 = acc[mt][nt][0] + bv.x; o.x = f2bf(v0 > 0.f ? v0 : 0.f);
      float v1 = acc[mt][nt][1] + bv.y; o.y = f2bf(v1 > 0.f ? v1 : 0.f);
      float v2 = acc[mt][nt][2] + bv.z; o.z = f2bf(v2 > 0.f ? v2 : 0.f);
      float v3 = acc[mt][nt][3] + bv.w; o.w = f2bf(v3 > 0.f ? v3 : 0.f);
      *(ushort4*)&h[nt * 16 + l15][Hbase] = o;
    }
  }
  __syncthreads();

  // layer 2 (transposed): D[Dout=128][node=32], K=256. Wave owns 32 Dout rows.
  f32x4 acc2[2][2];
#pragma unroll
  for (int mt = 0; mt < 2; ++mt)
#pragma unroll
    for (int nt = 0; nt < 2; ++nt) acc2[mt][nt] = (f32x4){0.f, 0.f, 0.f, 0.f};
#pragma unroll
  for (int kt = 0; kt < 8; ++kt) {
    bf8 wfr[2], xfr[2];
#pragma unroll
    for (int mt = 0; mt < 2; ++mt) {
      int Dtile = wave * 2 + mt;
      wfr[mt] = *(const bf8*)(W2p + ((size_t)(Dtile * 8 + kt) * 64 + lane) * 8);
    }
#pragma unroll
    for (int nt = 0; nt < 2; ++nt)
      xfr[nt] = *(const bf8*)&h[nt * 16 + l15][kt * 32 + l4 * 8];
#pragma unroll
    for (int mt = 0; mt < 2; ++mt)
#pragma unroll
      for (int nt = 0; nt < 2; ++nt)
        acc2[mt][nt] = __builtin_amdgcn_mfma_f32_16x16x32_bf16(wfr[mt], xfr[nt], acc2[mt][nt], 0, 0, 0);
  }
  // epilogue: bias + bf16 residual + coalesced NORMAL float4 stores
#pragma unroll
  for (int mt = 0; mt < 2; ++mt) {
    int Dbase = (wave * 2 + mt) * 16 + l4 * 4;
    float4 bv = *(const float4*)(b2 + Dbase);
#pragma unroll
    for (int nt = 0; nt < 2; ++nt) {
      int node = row0 + nt * 16 + l15;
      float4 o;
      o.x = bf2f(resid[mt][nt].x) + acc2[mt][nt][0] + bv.x;
      o.y = bf2f(resid[mt][nt].y) + acc2[mt][nt][1] + bv.y;
      o.z = bf2f(resid[mt][nt].z) + acc2[mt][nt][2] + bv.z;
      o.w = bf2f(resid[mt][nt].w) + acc2[mt][nt][3] + bv.w;
      *(float4*)(out + (size_t)node * DD + Dbase) = o;
    }
  }
}

extern "C" void kernel_launch(void* const* d_in, const int* in_sizes, int n_in,
                              void* d_out, int out_size, void* d_ws, size_t ws_size,
                              hipStream_t stream) {
  const float* nodes = (const float*)d_in[0];
  const int* senders = (const int*)d_in[1];
  const int* receivers = (const int*)d_in[2];
  const float* Wm1 = (const float*)d_in[3];
  const float* bm1 = (const float*)d_in[4];
  const float* Wm2 = (const float*)d_in[5];
  const float* bm2 = (const float*)d_in[6];
  const float* Wn1 = (const float*)d_in[7];
  const float* bn1 = (const float*)d_in[8];
  const float* Wn2 = (const float*)d_in[9];
  const float* bn2 = (const float*)d_in[10];
  float* out = (float*)d_out;

  char* ws = (char*)d_ws;
  unsigned char* Mb    = (unsigned char*)(ws);                // (NN+1)*DD = 12,800,128 B (pad to 12,800,256)
  unsigned short* Xb   = (unsigned short*)(ws + 12800256);    // 25,600,000 B
  int* cnt    = (int*)(ws + 38400256);                        // 400,000 B
  int* ebuf   = (int*)(ws + 38800256);                        // 12,800,000 B (NN*CAP*4)
  unsigned short* Wm1p = (unsigned short*)(ws + 51600256);    // 65,536 B
  unsigned short* Wm2p = (unsigned short*)(ws + 51665792);    // 65,536 B
  unsigned short* Wn1p = (unsigned short*)(ws + 51731328);    // 131,072 B
  unsigned short* Wn2p = (unsigned short*)(ws + 51862400);    // 65,536 B

  hipMemsetAsync(cnt, 0, NN * sizeof(int), stream);
  hipMemsetAsync(ebuf, 0x01, (size_t)NN * CAP * sizeof(int), stream);  // sentinel 0x01010101 > NN
  prep<<<2048, 256, 0, stream>>>(Wm1, Wm2, Wn1, Wn2, Wm1p, Wm2p, Wn1p, Wn2p,
                                 cnt, nodes, Xb, Mb, senders, receivers, ebuf);
  msg_mlp<<<1563, 512, 0, stream>>>(Xb, Wm1p, bm1, Wm2p, bm2, Mb);
  node_fused<<<3125, 256, 0, stream>>>(Xb, Mb, ebuf, cnt,
                                       Wn1p, bn1, Wn2p, bn2, out);
}

// Round 10
// 217.429 us; speedup vs baseline: 1.0434x; 1.0434x over previous
//
#include <hip/hip_runtime.h>

#define NN 100000
#define DD 128
#define HH 256
#define NE 600000
#define CAP 32   // max in-degree bucket capacity; Poisson(mean 6) => P(>=32) ~ 4e-16

typedef short bf8 __attribute__((ext_vector_type(8)));       // 8 bf16 (4 VGPRs)
typedef float f32x4 __attribute__((ext_vector_type(4)));     // MFMA C/D
typedef float f32x2 __attribute__((ext_vector_type(2)));
typedef unsigned short u16x8 __attribute__((ext_vector_type(8)));
typedef int i32x4 __attribute__((ext_vector_type(4)));

__device__ __forceinline__ unsigned short f2bf(float f) {
  unsigned int u = __builtin_bit_cast(unsigned int, f);
  u += 0x7fffu + ((u >> 16) & 1u);          // RNE
  return (unsigned short)(u >> 16);
}
__device__ __forceinline__ float bf2f(unsigned short h) {
  unsigned int u = ((unsigned int)h) << 16;
  return __builtin_bit_cast(float, u);
}

// ---- prep (2048 blocks): cnt zero + ebuf NN-prefill + nodes->bf16 Xb +
// Mb(fp8) zero-row + weight pack. ebuf prefilled with NN so gather's unused
// slots hit the Mb zero-row -> mask-free, branch-free gather (r8 structure;
// r9 showed moving the edge fill here costs net +9us vs msg-head fill).
__global__ __launch_bounds__(256) void prep(
    const float* __restrict__ Wm1, const float* __restrict__ Wm2,
    const float* __restrict__ Wn1, const float* __restrict__ Wn2,
    unsigned short* __restrict__ Pm1, unsigned short* __restrict__ Pm2,
    unsigned short* __restrict__ Pn1, unsigned short* __restrict__ Pn2,
    int* __restrict__ cnt,
    const float* __restrict__ nodes, unsigned short* __restrict__ Xb,
    unsigned char* __restrict__ Mb, int* __restrict__ ebuf) {
  int b = blockIdx.x;
  int gid = b * 256 + threadIdx.x;

  // zero cnt
  for (int i = gid; i < NN; i += 2048 * 256) cnt[i] = 0;

  // prefill ebuf with NN (3.2M ints; streaming)
  for (int i = gid; i < NN * CAP / 4; i += 2048 * 256)
    ((i32x4*)ebuf)[i] = (i32x4){NN, NN, NN, NN};

  // zero-row Mb[NN] (fp8 0x00 == 0.0f; unused gather slots point here)
  if (b == 0 && threadIdx.x < 8)
    ((i32x4*)(Mb + (size_t)NN * DD))[threadIdx.x] = (i32x4){0, 0, 0, 0};

  // nodes fp32 -> Xb bf16 (8 elems per iter)
  for (int i = gid; i < NN * DD / 8; i += 2048 * 256) {
    const float4 v0 = ((const float4*)nodes)[i * 2];
    const float4 v1 = ((const float4*)nodes)[i * 2 + 1];
    u16x8 o;
    o[0] = f2bf(v0.x); o[1] = f2bf(v0.y); o[2] = f2bf(v0.z); o[3] = f2bf(v0.w);
    o[4] = f2bf(v1.x); o[5] = f2bf(v1.y); o[6] = f2bf(v1.z); o[7] = f2bf(v1.w);
    ((u16x8*)Xb)[i] = o;
  }

  // weight packing on blocks 0..79
  // P[((nt*(K/32)+kt)*64 + lane)*8 + j] = W[kt*32+(lane>>4)*8+j][nt*16+(lane&15)]
  if (b < 80) {
    const float* W; unsigned short* P; int K, N, base;
    if (b < 16)      { W = Wm1; P = Pm1; K = 128; N = 256; base = 0;  }
    else if (b < 32) { W = Wm2; P = Pm2; K = 256; N = 128; base = 16; }
    else if (b < 64) { W = Wn1; P = Pn1; K = 256; N = 256; base = 32; }
    else             { W = Wn2; P = Pn2; K = 256; N = 128; base = 64; }
    int idx = (b - base) * 256 + threadIdx.x;
    int KT = K >> 5;
    int lane = idx & 63;
    int t = idx >> 6;
    int kt = t % KT, nt = t / KT;
    int n = nt * 16 + (lane & 15);
    int k0 = kt * 32 + (lane >> 4) * 8;
    unsigned short* dst = P + (size_t)idx * 8;
#pragma unroll
    for (int j = 0; j < 8; ++j) dst[j] = f2bf(W[(size_t)(k0 + j) * N + n]);
  }
}

// ---- message MLP: 512 thr / 8 waves / 64-row tile; edge-bucket fill at HEAD
// (fill here, not prep: its atomic/scatter latency overlaps this kernel's MFMA
// compute — r8 vs r9 A/B: msg-head fill wins by ~9us total).
// Mb output is fp8 e4m3 via HW cvt (halves gather bytes downstream).
__global__ __launch_bounds__(512) void msg_mlp(
    const unsigned short* __restrict__ Xb,
    const unsigned short* __restrict__ W1p, const float* __restrict__ b1,
    const unsigned short* __restrict__ W2p, const float* __restrict__ b2,
    unsigned char* __restrict__ Mb,
    const int* __restrict__ snd, const int* __restrict__ rcv,
    int* __restrict__ cnt, int* __restrict__ ebuf) {
  __shared__ __align__(16) unsigned short h[64][264];
  const int row0 = blockIdx.x * 64;
  const int tid = threadIdx.x;
  const int lane = tid & 63, wave = tid >> 6;   // 0..7
  const int l15 = lane & 15, l4 = lane >> 4;

  // folded CSR bucket fill (one edge per thread), overlapped with staging
  {
    int e = blockIdx.x * 512 + tid;
    if (e < NE) {
      int r = rcv[e];
      int pos = atomicAdd(&cnt[r], 1);
      if (pos < CAP) ebuf[r * CAP + pos] = snd[e];
    }
  }

  // stage X tile (64x128 bf16) from warm Xb
#pragma unroll
  for (int i = 0; i < 2; ++i) {
    int flat = (i * 512 + tid) * 8;
    int r = flat >> 7, c = flat & 127;
    u16x8 v = (u16x8)0;
    if (row0 + r < NN) v = *(const u16x8*)(Xb + (size_t)(row0 + r) * DD + c);
    *(u16x8*)&h[r][c] = v;
  }
  __syncthreads();

  // layer 1 (transposed): D[H=256][node=64], K=128. Wave owns 32 H rows.
  f32x4 acc[2][4];
#pragma unroll
  for (int mt = 0; mt < 2; ++mt)
#pragma unroll
    for (int nt = 0; nt < 4; ++nt) acc[mt][nt] = (f32x4){0.f, 0.f, 0.f, 0.f};
#pragma unroll
  for (int kt = 0; kt < 4; ++kt) {
    bf8 wfr[2], xfr[4];
#pragma unroll
    for (int mt = 0; mt < 2; ++mt) {
      int Htile = wave * 2 + mt;
      wfr[mt] = *(const bf8*)(W1p + ((size_t)(Htile * 4 + kt) * 64 + lane) * 8);
    }
#pragma unroll
    for (int nt = 0; nt < 4; ++nt)
      xfr[nt] = *(const bf8*)&h[nt * 16 + l15][kt * 32 + l4 * 8];
#pragma unroll
    for (int mt = 0; mt < 2; ++mt)
#pragma unroll
      for (int nt = 0; nt < 4; ++nt)
        acc[mt][nt] = __builtin_amdgcn_mfma_f32_16x16x32_bf16(wfr[mt], xfr[nt], acc[mt][nt], 0, 0, 0);
  }
  __syncthreads();

  // epilogue 1: bias + relu, vectorized writes h[node][H]
#pragma unroll
  for (int mt = 0; mt < 2; ++mt) {
    int Hbase = wave * 32 + mt * 16 + l4 * 4;
    float4 bv = *(const float4*)(b1 + Hbase);
#pragma unroll
    for (int nt = 0; nt < 4; ++nt) {
      ushort4 o;
      float v0 = acc[mt][nt][0] + bv.x; o.x = f2bf(v0 > 0.f ? v0 : 0.f);
      float v1 = acc[mt][nt][1] + bv.y; o.y = f2bf(v1 > 0.f ? v1 : 0.f);
      float v2 = acc[mt][nt][2] + bv.z; o.z = f2bf(v2 > 0.f ? v2 : 0.f);
      float v3 = acc[mt][nt][3] + bv.w; o.w = f2bf(v3 > 0.f ? v3 : 0.f);
      *(ushort4*)&h[nt * 16 + l15][Hbase] = o;
    }
  }
  __syncthreads();

  // layer 2 (transposed): D[Dout=128][node=64], K=256. Wave owns 16 Dout rows.
  f32x4 acc2[4];
#pragma unroll
  for (int nt = 0; nt < 4; ++nt) acc2[nt] = (f32x4){0.f, 0.f, 0.f, 0.f};
#pragma unroll
  for (int kt = 0; kt < 8; ++kt) {
    bf8 wfr, xfr[4];
    wfr = *(const bf8*)(W2p + ((size_t)(wave * 8 + kt) * 64 + lane) * 8);
#pragma unroll
    for (int nt = 0; nt < 4; ++nt)
      xfr[nt] = *(const bf8*)&h[nt * 16 + l15][kt * 32 + l4 * 8];
#pragma unroll
    for (int nt = 0; nt < 4; ++nt)
      acc2[nt] = __builtin_amdgcn_mfma_f32_16x16x32_bf16(wfr, xfr[nt], acc2[nt], 0, 0, 0);
  }
  // epilogue 2: bias + store Mb fp8 (HW RNE convert, 4B/lane)
  {
    int Dbase = wave * 16 + l4 * 4;
    float4 bv = *(const float4*)(b2 + Dbase);
#pragma unroll
    for (int nt = 0; nt < 4; ++nt) {
      int node = row0 + nt * 16 + l15;
      if (node < NN) {
        int p = 0;
        p = __builtin_amdgcn_cvt_pk_fp8_f32(acc2[nt][0] + bv.x, acc2[nt][1] + bv.y, p, false);
        p = __builtin_amdgcn_cvt_pk_fp8_f32(acc2[nt][2] + bv.z, acc2[nt][3] + bv.w, p, true);
        *(unsigned int*)(Mb + (size_t)node * DD + Dbase) = (unsigned int)p;
      }
    }
  }
}

// ---- node MLP fused with gather: 256 thr / 4 waves / 32-row tile (grid 3125).
// NEW vs r8: round-0 gather EARLY-ISSUE — the half-wave's 8 slots are read
// straight from global ebuf at kernel head (valid-or-NN via prefill, no
// clamp) and the 8 random Mb loads are issued BEFORE the ebuf/X staging, so
// their ~500-900cy latency runs concurrent with staging instead of after the
// barrier. __launch_bounds__(256,8) pins VGPR<=64 (r2's occupancy cliff).
// Rounds 1-3 via the LDS slot tile as before; straight-line, mask-free.
__global__ __launch_bounds__(256, 8) void node_fused(
    const unsigned short* __restrict__ Xb, const unsigned char* __restrict__ Mb,
    const int* __restrict__ ebuf, const int* __restrict__ cnt,
    const unsigned short* __restrict__ W1p, const float* __restrict__ b1,
    const unsigned short* __restrict__ W2p, const float* __restrict__ b2,
    float* __restrict__ out) {
  __shared__ __align__(16) unsigned short h[32][264];
  const int row0 = blockIdx.x * 32;
  const int tid = threadIdx.x;
  const int lane = tid & 63, wave = tid >> 6;   // 0..3
  const int l15 = lane & 15, l4 = lane >> 4;
  const int halfid = lane >> 5, sub = lane & 31;

  // ---- EARLY: round-0 slots from global (broadcast within half-wave) ----
  int s0[8];
  {
    const int* gsl = ebuf + (size_t)(row0 + wave * 2 + halfid) * CAP;
#pragma unroll
    for (int u = 0; u < 8; ++u) s0[u] = gsl[u];
  }

  // degrees (half-wave per node: 8 half-waves x 4 rounds = 32 nodes)
  int degv[4];
#pragma unroll
  for (int t = 0; t < 4; ++t) {
    int node = row0 + t * 8 + wave * 2 + halfid;
    int d = cnt[node];
    degv[t] = d < CAP ? d : CAP;
  }

  // stage ebuf slot tile (32 nodes x 32 slots = 4KB) into agg region of h.
  // Slots stay valid until the deferred agg-write phase (after tails).
  {
    int idx = tid * 4;                      // 1024 ints total
    int r = idx >> 5, s = idx & 31;
    i32x4 v = __builtin_nontemporal_load((const i32x4*)(ebuf + (size_t)row0 * CAP + idx));
    *(i32x4*)(((int*)&h[r][128]) + s) = v;
  }

  // ---- EARLY: issue round-0 Mb loads (s0 already in flight ahead of the
  // staging loads; in-order returns mean s0 is back by the time the LDS
  // writes above drain). These fly during X staging + the barrier. ----
  unsigned int mv0[8];
#pragma unroll
  for (int u = 0; u < 8; ++u)
    mv0[u] = *(const unsigned int*)(Mb + (size_t)s0[u] * DD + sub * 4);

  // stage X tile (32x128 bf16) from Xb, cols 0..127 (read-once: nt)
#pragma unroll
  for (int i = 0; i < 2; ++i) {
    int flat = (i * 256 + tid) * 8;
    int r = flat >> 7, c = flat & 127;
    u16x8 v = __builtin_nontemporal_load((const u16x8*)(Xb + (size_t)(row0 + r) * DD + c));
    *(u16x8*)&h[r][c] = v;
  }
  __syncthreads();

  // ---- gather: round 0 consumes the early registers ----
  ushort4 oreg[4];
  {
    float a0 = 0.f, a1 = 0.f, a2 = 0.f, a3 = 0.f;
#pragma unroll
    for (int u = 0; u < 8; ++u) {
      f32x2 lo = __builtin_amdgcn_cvt_pk_f32_fp8((int)mv0[u], false);
      f32x2 hi = __builtin_amdgcn_cvt_pk_f32_fp8((int)mv0[u], true);
      a0 += lo[0]; a1 += lo[1]; a2 += hi[0]; a3 += hi[1];
    }
    ushort4 o;
    o.x = f2bf(a0); o.y = f2bf(a1); o.z = f2bf(a2); o.w = f2bf(a3);
    oreg[0] = o;
  }

  // ---- rounds 1-3: branch-free, mask-free, via LDS slot tile ----
#pragma unroll
  for (int t = 1; t < 4; ++t) {
    int ln = t * 8 + wave * 2 + halfid;
    const int* sl_p = (const int*)&h[ln][128];   // broadcast reads (same addr)
    unsigned int mv[8];
#pragma unroll
    for (int u = 0; u < 8; ++u)
      mv[u] = *(const unsigned int*)(Mb + (size_t)sl_p[u] * DD + sub * 4);
    float a0 = 0.f, a1 = 0.f, a2 = 0.f, a3 = 0.f;
#pragma unroll
    for (int u = 0; u < 8; ++u) {
      f32x2 lo = __builtin_amdgcn_cvt_pk_f32_fp8((int)mv[u], false);
      f32x2 hi = __builtin_amdgcn_cvt_pk_f32_fp8((int)mv[u], true);
      a0 += lo[0]; a1 += lo[1]; a2 += hi[0]; a3 += hi[1];
    }
    ushort4 o;
    o.x = f2bf(a0); o.y = f2bf(a1); o.z = f2bf(a2); o.w = f2bf(a3);
    oreg[t] = o;
  }

  // ---- tails (deg > 8, rare): unpack partial, add, repack ----
#pragma unroll
  for (int t = 0; t < 4; ++t) {
    int deg = degv[t];
    if (deg > 8) {
      int ln = t * 8 + wave * 2 + halfid;
      const int* sl_p = (const int*)&h[ln][128];
      float a0 = bf2f(oreg[t].x), a1 = bf2f(oreg[t].y);
      float a2 = bf2f(oreg[t].z), a3 = bf2f(oreg[t].w);
      for (int bb = 8; bb < deg; bb += 8) {
        unsigned int mv[8];
#pragma unroll
        for (int u = 0; u < 8; ++u)
          mv[u] = *(const unsigned int*)(Mb + (size_t)sl_p[bb + u] * DD + sub * 4);
#pragma unroll
        for (int u = 0; u < 8; ++u) {
          f32x2 lo = __builtin_amdgcn_cvt_pk_f32_fp8((int)mv[u], false);
          f32x2 hi = __builtin_amdgcn_cvt_pk_f32_fp8((int)mv[u], true);
          a0 += lo[0]; a1 += lo[1]; a2 += hi[0]; a3 += hi[1];
        }
      }
      ushort4 o;
      o.x = f2bf(a0); o.y = f2bf(a1); o.z = f2bf(a2); o.w = f2bf(a3);
      oreg[t] = o;
    }
  }

  // ---- single agg write phase (slots consumed; each half owns its rows) ----
#pragma unroll
  for (int t = 0; t < 4; ++t) {
    int ln = t * 8 + wave * 2 + halfid;
    *(ushort4*)&h[ln][128 + sub * 4] = oreg[t];
  }
  __syncthreads();

  // residual snapshot (bf16, before epilogue-1 overwrites h cols 0..127)
  ushort4 resid[2][2];
#pragma unroll
  for (int mt = 0; mt < 2; ++mt)
#pragma unroll
    for (int nt = 0; nt < 2; ++nt)
      resid[mt][nt] = *(ushort4*)&h[nt * 16 + l15][(wave * 2 + mt) * 16 + l4 * 4];

  // layer 1 (transposed): D[H=256][node=32], K=256. Wave owns 64 H rows (4 tiles).
  f32x4 acc[4][2];
#pragma unroll
  for (int mt = 0; mt < 4; ++mt)
#pragma unroll
    for (int nt = 0; nt < 2; ++nt) acc[mt][nt] = (f32x4){0.f, 0.f, 0.f, 0.f};
#pragma unroll
  for (int kt = 0; kt < 8; ++kt) {
    bf8 wfr[4], xfr[2];
#pragma unroll
    for (int mt = 0; mt < 4; ++mt) {
      int Htile = wave * 4 + mt;
      wfr[mt] = *(const bf8*)(W1p + ((size_t)(Htile * 8 + kt) * 64 + lane) * 8);
    }
#pragma unroll
    for (int nt = 0; nt < 2; ++nt)
      xfr[nt] = *(const bf8*)&h[nt * 16 + l15][kt * 32 + l4 * 8];
#pragma unroll
    for (int mt = 0; mt < 4; ++mt)
#pragma unroll
      for (int nt = 0; nt < 2; ++nt)
        acc[mt][nt] = __builtin_amdgcn_mfma_f32_16x16x32_bf16(wfr[mt], xfr[nt], acc[mt][nt], 0, 0, 0);
  }
  __syncthreads();

  // epilogue 1: bias + relu
#pragma unroll
  for (int mt = 0; mt < 4; ++mt) {
    int Hbase = (wave * 4 + mt) * 16 + l4 * 4;
    float4 bv = *(const float4*)(b1 + Hbase);
#pragma unroll
    for (int nt = 0; nt < 2; ++nt) {
      ushort4 o;
      float v0 = acc[mt][nt][0] + bv.x; o.x = f2bf(v0 > 0.f ? v0 : 0.f);
      float v1 = acc[mt][nt][1] + bv.y; o.y = f2bf(v1 > 0.f ? v1 : 0.f);
      float v2 = acc[mt][nt][2] + bv.z; o.z = f2bf(v2 > 0.f ? v2 : 0.f);
      float v3 = acc[mt][nt][3] + bv.w; o.w = f2bf(v3 > 0.f ? v3 : 0.f);
      *(ushort4*)&h[nt * 16 + l15][Hbase] = o;
    }
  }
  __syncthreads();

  // layer 2 (transposed): D[Dout=128][node=32], K=256. Wave owns 32 Dout rows.
  f32x4 acc2[2][2];
#pragma unroll
  for (int mt = 0; mt < 2; ++mt)
#pragma unroll
    for (int nt = 0; nt < 2; ++nt) acc2[mt][nt] = (f32x4){0.f, 0.f, 0.f, 0.f};
#pragma unroll
  for (int kt = 0; kt < 8; ++kt) {
    bf8 wfr[2], xfr[2];
#pragma unroll
    for (int mt = 0; mt < 2; ++mt) {
      int Dtile = wave * 2 + mt;
      wfr[mt] = *(const bf8*)(W2p + ((size_t)(Dtile * 8 + kt) * 64 + lane) * 8);
    }
#pragma unroll
    for (int nt = 0; nt < 2; ++nt)
      xfr[nt] = *(const bf8*)&h[nt * 16 + l15][kt * 32 + l4 * 8];
#pragma unroll
    for (int mt = 0; mt < 2; ++mt)
#pragma unroll
      for (int nt = 0; nt < 2; ++nt)
        acc2[mt][nt] = __builtin_amdgcn_mfma_f32_16x16x32_bf16(wfr[mt], xfr[nt], acc2[mt][nt], 0, 0, 0);
  }
  // epilogue: bias + bf16 residual + coalesced NORMAL float4 stores
#pragma unroll
  for (int mt = 0; mt < 2; ++mt) {
    int Dbase = (wave * 2 + mt) * 16 + l4 * 4;
    float4 bv = *(const float4*)(b2 + Dbase);
#pragma unroll
    for (int nt = 0; nt < 2; ++nt) {
      int node = row0 + nt * 16 + l15;
      float4 o;
      o.x = bf2f(resid[mt][nt].x) + acc2[mt][nt][0] + bv.x;
      o.y = bf2f(resid[mt][nt].y) + acc2[mt][nt][1] + bv.y;
      o.z = bf2f(resid[mt][nt].z) + acc2[mt][nt][2] + bv.z;
      o.w = bf2f(resid[mt][nt].w) + acc2[mt][nt][3] + bv.w;
      *(float4*)(out + (size_t)node * DD + Dbase) = o;
    }
  }
}

extern "C" void kernel_launch(void* const* d_in, const int* in_sizes, int n_in,
                              void* d_out, int out_size, void* d_ws, size_t ws_size,
                              hipStream_t stream) {
  const float* nodes = (const float*)d_in[0];
  const int* senders = (const int*)d_in[1];
  const int* receivers = (const int*)d_in[2];
  const float* Wm1 = (const float*)d_in[3];
  const float* bm1 = (const float*)d_in[4];
  const float* Wm2 = (const float*)d_in[5];
  const float* bm2 = (const float*)d_in[6];
  const float* Wn1 = (const float*)d_in[7];
  const float* bn1 = (const float*)d_in[8];
  const float* Wn2 = (const float*)d_in[9];
  const float* bn2 = (const float*)d_in[10];
  float* out = (float*)d_out;

  char* ws = (char*)d_ws;
  unsigned char* Mb    = (unsigned char*)(ws);                // (NN+1)*DD = 12,800,128 B (pad to 12,800,256)
  unsigned short* Xb   = (unsigned short*)(ws + 12800256);    // 25,600,000 B
  int* cnt    = (int*)(ws + 38400256);                        // 400,000 B
  int* ebuf   = (int*)(ws + 38800256);                        // 12,800,000 B (NN*CAP*4)
  unsigned short* Wm1p = (unsigned short*)(ws + 51600256);    // 65,536 B
  unsigned short* Wm2p = (unsigned short*)(ws + 51665792);    // 65,536 B
  unsigned short* Wn1p = (unsigned short*)(ws + 51731328);    // 131,072 B
  unsigned short* Wn2p = (unsigned short*)(ws + 51862400);    // 65,536 B

  prep<<<2048, 256, 0, stream>>>(Wm1, Wm2, Wn1, Wn2, Wm1p, Wm2p, Wn1p, Wn2p,
                                 cnt, nodes, Xb, Mb, ebuf);
  msg_mlp<<<1563, 512, 0, stream>>>(Xb, Wm1p, bm1, Wm2p, bm2, Mb,
                                    senders, receivers, cnt, ebuf);
  node_fused<<<3125, 256, 0, stream>>>(Xb, Mb, ebuf, cnt,
                                       Wn1p, bn1, Wn2p, bn2, out);
}

// Round 12
// 215.205 us; speedup vs baseline: 1.0541x; 1.0103x over previous
//
#include <hip/hip_runtime.h>

#define NN 100000
#define DD 128
#define HH 256
#define NE 600000
#define CAP 32   // max in-degree bucket capacity; Poisson(mean 6) => P(>=32) ~ 4e-16

typedef short bf8 __attribute__((ext_vector_type(8)));       // 8 bf16 (4 VGPRs)
typedef float f32x4 __attribute__((ext_vector_type(4)));     // MFMA C/D
typedef float f32x2 __attribute__((ext_vector_type(2)));
typedef unsigned short u16x8 __attribute__((ext_vector_type(8)));
typedef int i32x4 __attribute__((ext_vector_type(4)));

__device__ __forceinline__ unsigned short f2bf(float f) {
  unsigned int u = __builtin_bit_cast(unsigned int, f);
  u += 0x7fffu + ((u >> 16) & 1u);          // RNE
  return (unsigned short)(u >> 16);
}
__device__ __forceinline__ float bf2f(unsigned short h) {
  unsigned int u = ((unsigned int)h) << 16;
  return __builtin_bit_cast(float, u);
}

// ---- prep (2048 blocks): cnt zero + ebuf NN-prefill + nodes->bf16 Xb +
// Mb(fp8) zero-row + weight pack. ebuf prefilled with NN so gather's unused
// slots hit the Mb zero-row -> mask-free, branch-free gather.
__global__ __launch_bounds__(256) void prep(
    const float* __restrict__ Wm1, const float* __restrict__ Wm2,
    const float* __restrict__ Wn1, const float* __restrict__ Wn2,
    unsigned short* __restrict__ Pm1, unsigned short* __restrict__ Pm2,
    unsigned short* __restrict__ Pn1, unsigned short* __restrict__ Pn2,
    int* __restrict__ cnt,
    const float* __restrict__ nodes, unsigned short* __restrict__ Xb,
    unsigned char* __restrict__ Mb, int* __restrict__ ebuf) {
  int b = blockIdx.x;
  int gid = b * 256 + threadIdx.x;

  // zero cnt
  for (int i = gid; i < NN; i += 2048 * 256) cnt[i] = 0;

  // prefill ebuf with NN (3.2M ints; streaming)
  for (int i = gid; i < NN * CAP / 4; i += 2048 * 256)
    ((i32x4*)ebuf)[i] = (i32x4){NN, NN, NN, NN};

  // zero-row Mb[NN] (fp8 0x00 == 0.0f; unused gather slots point here)
  if (b == 0 && threadIdx.x < 8)
    ((i32x4*)(Mb + (size_t)NN * DD))[threadIdx.x] = (i32x4){0, 0, 0, 0};

  // nodes fp32 -> Xb bf16 (8 elems per iter)
  for (int i = gid; i < NN * DD / 8; i += 2048 * 256) {
    const float4 v0 = ((const float4*)nodes)[i * 2];
    const float4 v1 = ((const float4*)nodes)[i * 2 + 1];
    u16x8 o;
    o[0] = f2bf(v0.x); o[1] = f2bf(v0.y); o[2] = f2bf(v0.z); o[3] = f2bf(v0.w);
    o[4] = f2bf(v1.x); o[5] = f2bf(v1.y); o[6] = f2bf(v1.z); o[7] = f2bf(v1.w);
    ((u16x8*)Xb)[i] = o;
  }

  // weight packing on blocks 0..79
  // P[((nt*(K/32)+kt)*64 + lane)*8 + j] = W[kt*32+(lane>>4)*8+j][nt*16+(lane&15)]
  if (b < 80) {
    const float* W; unsigned short* P; int K, N, base;
    if (b < 16)      { W = Wm1; P = Pm1; K = 128; N = 256; base = 0;  }
    else if (b < 32) { W = Wm2; P = Pm2; K = 256; N = 128; base = 16; }
    else if (b < 64) { W = Wn1; P = Pn1; K = 256; N = 256; base = 32; }
    else             { W = Wn2; P = Pn2; K = 256; N = 128; base = 64; }
    int idx = (b - base) * 256 + threadIdx.x;
    int KT = K >> 5;
    int lane = idx & 63;
    int t = idx >> 6;
    int kt = t % KT, nt = t / KT;
    int n = nt * 16 + (lane & 15);
    int k0 = kt * 32 + (lane >> 4) * 8;
    unsigned short* dst = P + (size_t)idx * 8;
#pragma unroll
    for (int j = 0; j < 8; ++j) dst[j] = f2bf(W[(size_t)(k0 + j) * N + n]);
  }
}

// ---- message MLP: 512 thr / 8 waves / 64-row tile. Edge-bucket fill moved
// AFTER the stage-barrier: __syncthreads drains vmcnt(0), so a pre-barrier
// scattered ebuf store (~800cy random) stalled every block's FIRST barrier
// with only the short stage phase to hide it. Issued here, the atomic->store
// chain drains at the L1->epi1 barrier, under 32 MFMAs + weight streams.
__global__ __launch_bounds__(512) void msg_mlp(
    const unsigned short* __restrict__ Xb,
    const unsigned short* __restrict__ W1p, const float* __restrict__ b1,
    const unsigned short* __restrict__ W2p, const float* __restrict__ b2,
    unsigned char* __restrict__ Mb,
    const int* __restrict__ snd, const int* __restrict__ rcv,
    int* __restrict__ cnt, int* __restrict__ ebuf) {
  __shared__ __align__(16) unsigned short h[64][264];
  const int row0 = blockIdx.x * 64;
  const int tid = threadIdx.x;
  const int lane = tid & 63, wave = tid >> 6;   // 0..7
  const int l15 = lane & 15, l4 = lane >> 4;

  // stage X tile (64x128 bf16) from warm Xb
#pragma unroll
  for (int i = 0; i < 2; ++i) {
    int flat = (i * 512 + tid) * 8;
    int r = flat >> 7, c = flat & 127;
    u16x8 v = (u16x8)0;
    if (row0 + r < NN) v = *(const u16x8*)(Xb + (size_t)(row0 + r) * DD + c);
    *(u16x8*)&h[r][c] = v;
  }
  __syncthreads();

  // folded CSR bucket fill (one edge per thread) — issued after the first
  // barrier so its scatter store drains under the L1 MFMA phase.
  {
    int e = blockIdx.x * 512 + tid;
    if (e < NE) {
      int r = rcv[e];
      int pos = atomicAdd(&cnt[r], 1);
      if (pos < CAP) ebuf[r * CAP + pos] = snd[e];
    }
  }

  // layer 1 (transposed): D[H=256][node=64], K=128. Wave owns 32 H rows.
  f32x4 acc[2][4];
#pragma unroll
  for (int mt = 0; mt < 2; ++mt)
#pragma unroll
    for (int nt = 0; nt < 4; ++nt) acc[mt][nt] = (f32x4){0.f, 0.f, 0.f, 0.f};
#pragma unroll
  for (int kt = 0; kt < 4; ++kt) {
    bf8 wfr[2], xfr[4];
#pragma unroll
    for (int mt = 0; mt < 2; ++mt) {
      int Htile = wave * 2 + mt;
      wfr[mt] = *(const bf8*)(W1p + ((size_t)(Htile * 4 + kt) * 64 + lane) * 8);
    }
#pragma unroll
    for (int nt = 0; nt < 4; ++nt)
      xfr[nt] = *(const bf8*)&h[nt * 16 + l15][kt * 32 + l4 * 8];
#pragma unroll
    for (int mt = 0; mt < 2; ++mt)
#pragma unroll
      for (int nt = 0; nt < 4; ++nt)
        acc[mt][nt] = __builtin_amdgcn_mfma_f32_16x16x32_bf16(wfr[mt], xfr[nt], acc[mt][nt], 0, 0, 0);
  }
  __syncthreads();

  // epilogue 1: bias + relu, vectorized writes h[node][H]
#pragma unroll
  for (int mt = 0; mt < 2; ++mt) {
    int Hbase = wave * 32 + mt * 16 + l4 * 4;
    float4 bv = *(const float4*)(b1 + Hbase);
#pragma unroll
    for (int nt = 0; nt < 4; ++nt) {
      ushort4 o;
      float v0 = acc[mt][nt][0] + bv.x; o.x = f2bf(v0 > 0.f ? v0 : 0.f);
      float v1 = acc[mt][nt][1] + bv.y; o.y = f2bf(v1 > 0.f ? v1 : 0.f);
      float v2 = acc[mt][nt][2] + bv.z; o.z = f2bf(v2 > 0.f ? v2 : 0.f);
      float v3 = acc[mt][nt][3] + bv.w; o.w = f2bf(v3 > 0.f ? v3 : 0.f);
      *(ushort4*)&h[nt * 16 + l15][Hbase] = o;
    }
  }
  __syncthreads();

  // layer 2 (transposed): D[Dout=128][node=64], K=256. Wave owns 16 Dout rows.
  f32x4 acc2[4];
#pragma unroll
  for (int nt = 0; nt < 4; ++nt) acc2[nt] = (f32x4){0.f, 0.f, 0.f, 0.f};
#pragma unroll
  for (int kt = 0; kt < 8; ++kt) {
    bf8 wfr, xfr[4];
    wfr = *(const bf8*)(W2p + ((size_t)(wave * 8 + kt) * 64 + lane) * 8);
#pragma unroll
    for (int nt = 0; nt < 4; ++nt)
      xfr[nt] = *(const bf8*)&h[nt * 16 + l15][kt * 32 + l4 * 8];
#pragma unroll
    for (int nt = 0; nt < 4; ++nt)
      acc2[nt] = __builtin_amdgcn_mfma_f32_16x16x32_bf16(wfr, xfr[nt], acc2[nt], 0, 0, 0);
  }
  // epilogue 2: bias + store Mb fp8 (HW RNE convert, 4B/lane)
  {
    int Dbase = wave * 16 + l4 * 4;
    float4 bv = *(const float4*)(b2 + Dbase);
#pragma unroll
    for (int nt = 0; nt < 4; ++nt) {
      int node = row0 + nt * 16 + l15;
      if (node < NN) {
        int p = 0;
        p = __builtin_amdgcn_cvt_pk_fp8_f32(acc2[nt][0] + bv.x, acc2[nt][1] + bv.y, p, false);
        p = __builtin_amdgcn_cvt_pk_fp8_f32(acc2[nt][2] + bv.z, acc2[nt][3] + bv.w, p, true);
        *(unsigned int*)(Mb + (size_t)node * DD + Dbase) = (unsigned int)p;
      }
    }
  }
}

// ---- node MLP fused with gather: 256 thr / 4 waves / 32-row tile (grid 3125).
// Early-issue round-0 gather kept (mechanism sound), but launch_bounds relaxed
// to (256,6): r10's (256,8) forced VGPR 52->32 and SPILLED (~+11MB scratch
// traffic in WRITE/FETCH, occupancy gain fully offset). 6 waves/SIMD allows
// ~85 VGPR — fits the ~68-reg live set with no spill, still > r9's 4 waves.
__global__ __launch_bounds__(256, 6) void node_fused(
    const unsigned short* __restrict__ Xb, const unsigned char* __restrict__ Mb,
    const int* __restrict__ ebuf, const int* __restrict__ cnt,
    const unsigned short* __restrict__ W1p, const float* __restrict__ b1,
    const unsigned short* __restrict__ W2p, const float* __restrict__ b2,
    float* __restrict__ out) {
  __shared__ __align__(16) unsigned short h[32][264];
  const int row0 = blockIdx.x * 32;
  const int tid = threadIdx.x;
  const int lane = tid & 63, wave = tid >> 6;   // 0..3
  const int l15 = lane & 15, l4 = lane >> 4;
  const int halfid = lane >> 5, sub = lane & 31;

  // ---- EARLY: round-0 slots from global (broadcast within half-wave) ----
  int s0[8];
  {
    const int* gsl = ebuf + (size_t)(row0 + wave * 2 + halfid) * CAP;
#pragma unroll
    for (int u = 0; u < 8; ++u) s0[u] = gsl[u];
  }

  // degrees (half-wave per node: 8 half-waves x 4 rounds = 32 nodes)
  int degv[4];
#pragma unroll
  for (int t = 0; t < 4; ++t) {
    int node = row0 + t * 8 + wave * 2 + halfid;
    int d = cnt[node];
    degv[t] = d < CAP ? d : CAP;
  }

  // stage ebuf slot tile (32 nodes x 32 slots = 4KB) into agg region of h.
  // Slots stay valid until the deferred agg-write phase (after tails).
  {
    int idx = tid * 4;                      // 1024 ints total
    int r = idx >> 5, s = idx & 31;
    i32x4 v = __builtin_nontemporal_load((const i32x4*)(ebuf + (size_t)row0 * CAP + idx));
    *(i32x4*)(((int*)&h[r][128]) + s) = v;
  }

  // ---- EARLY: issue round-0 Mb loads; they fly during X staging + barrier ----
  unsigned int mv0[8];
#pragma unroll
  for (int u = 0; u < 8; ++u)
    mv0[u] = *(const unsigned int*)(Mb + (size_t)s0[u] * DD + sub * 4);

  // stage X tile (32x128 bf16) from Xb, cols 0..127 (read-once: nt)
#pragma unroll
  for (int i = 0; i < 2; ++i) {
    int flat = (i * 256 + tid) * 8;
    int r = flat >> 7, c = flat & 127;
    u16x8 v = __builtin_nontemporal_load((const u16x8*)(Xb + (size_t)(row0 + r) * DD + c));
    *(u16x8*)&h[r][c] = v;
  }
  __syncthreads();

  // ---- gather: round 0 consumes the early registers ----
  ushort4 oreg[4];
  {
    float a0 = 0.f, a1 = 0.f, a2 = 0.f, a3 = 0.f;
#pragma unroll
    for (int u = 0; u < 8; ++u) {
      f32x2 lo = __builtin_amdgcn_cvt_pk_f32_fp8((int)mv0[u], false);
      f32x2 hi = __builtin_amdgcn_cvt_pk_f32_fp8((int)mv0[u], true);
      a0 += lo[0]; a1 += lo[1]; a2 += hi[0]; a3 += hi[1];
    }
    ushort4 o;
    o.x = f2bf(a0); o.y = f2bf(a1); o.z = f2bf(a2); o.w = f2bf(a3);
    oreg[0] = o;
  }

  // ---- rounds 1-3: branch-free, mask-free, via LDS slot tile ----
#pragma unroll
  for (int t = 1; t < 4; ++t) {
    int ln = t * 8 + wave * 2 + halfid;
    const int* sl_p = (const int*)&h[ln][128];   // broadcast reads (same addr)
    unsigned int mv[8];
#pragma unroll
    for (int u = 0; u < 8; ++u)
      mv[u] = *(const unsigned int*)(Mb + (size_t)sl_p[u] * DD + sub * 4);
    float a0 = 0.f, a1 = 0.f, a2 = 0.f, a3 = 0.f;
#pragma unroll
    for (int u = 0; u < 8; ++u) {
      f32x2 lo = __builtin_amdgcn_cvt_pk_f32_fp8((int)mv[u], false);
      f32x2 hi = __builtin_amdgcn_cvt_pk_f32_fp8((int)mv[u], true);
      a0 += lo[0]; a1 += lo[1]; a2 += hi[0]; a3 += hi[1];
    }
    ushort4 o;
    o.x = f2bf(a0); o.y = f2bf(a1); o.z = f2bf(a2); o.w = f2bf(a3);
    oreg[t] = o;
  }

  // ---- tails (deg > 8, rare): unpack partial, add, repack ----
#pragma unroll
  for (int t = 0; t < 4; ++t) {
    int deg = degv[t];
    if (deg > 8) {
      int ln = t * 8 + wave * 2 + halfid;
      const int* sl_p = (const int*)&h[ln][128];
      float a0 = bf2f(oreg[t].x), a1 = bf2f(oreg[t].y);
      float a2 = bf2f(oreg[t].z), a3 = bf2f(oreg[t].w);
      for (int bb = 8; bb < deg; bb += 8) {
        unsigned int mv[8];
#pragma unroll
        for (int u = 0; u < 8; ++u)
          mv[u] = *(const unsigned int*)(Mb + (size_t)sl_p[bb + u] * DD + sub * 4);
#pragma unroll
        for (int u = 0; u < 8; ++u) {
          f32x2 lo = __builtin_amdgcn_cvt_pk_f32_fp8((int)mv[u], false);
          f32x2 hi = __builtin_amdgcn_cvt_pk_f32_fp8((int)mv[u], true);
          a0 += lo[0]; a1 += lo[1]; a2 += hi[0]; a3 += hi[1];
        }
      }
      ushort4 o;
      o.x = f2bf(a0); o.y = f2bf(a1); o.z = f2bf(a2); o.w = f2bf(a3);
      oreg[t] = o;
    }
  }

  // ---- single agg write phase (slots consumed; each half owns its rows) ----
#pragma unroll
  for (int t = 0; t < 4; ++t) {
    int ln = t * 8 + wave * 2 + halfid;
    *(ushort4*)&h[ln][128 + sub * 4] = oreg[t];
  }
  __syncthreads();

  // residual snapshot (bf16, before epilogue-1 overwrites h cols 0..127)
  ushort4 resid[2][2];
#pragma unroll
  for (int mt = 0; mt < 2; ++mt)
#pragma unroll
    for (int nt = 0; nt < 2; ++nt)
      resid[mt][nt] = *(ushort4*)&h[nt * 16 + l15][(wave * 2 + mt) * 16 + l4 * 4];

  // layer 1 (transposed): D[H=256][node=32], K=256. Wave owns 64 H rows (4 tiles).
  f32x4 acc[4][2];
#pragma unroll
  for (int mt = 0; mt < 4; ++mt)
#pragma unroll
    for (int nt = 0; nt < 2; ++nt) acc[mt][nt] = (f32x4){0.f, 0.f, 0.f, 0.f};
#pragma unroll
  for (int kt = 0; kt < 8; ++kt) {
    bf8 wfr[4], xfr[2];
#pragma unroll
    for (int mt = 0; mt < 4; ++mt) {
      int Htile = wave * 4 + mt;
      wfr[mt] = *(const bf8*)(W1p + ((size_t)(Htile * 8 + kt) * 64 + lane) * 8);
    }
#pragma unroll
    for (int nt = 0; nt < 2; ++nt)
      xfr[nt] = *(const bf8*)&h[nt * 16 + l15][kt * 32 + l4 * 8];
#pragma unroll
    for (int mt = 0; mt < 4; ++mt)
#pragma unroll
      for (int nt = 0; nt < 2; ++nt)
        acc[mt][nt] = __builtin_amdgcn_mfma_f32_16x16x32_bf16(wfr[mt], xfr[nt], acc[mt][nt], 0, 0, 0);
  }
  __syncthreads();

  // epilogue 1: bias + relu
#pragma unroll
  for (int mt = 0; mt < 4; ++mt) {
    int Hbase = (wave * 4 + mt) * 16 + l4 * 4;
    float4 bv = *(const float4*)(b1 + Hbase);
#pragma unroll
    for (int nt = 0; nt < 2; ++nt) {
      ushort4 o;
      float v0 = acc[mt][nt][0] + bv.x; o.x = f2bf(v0 > 0.f ? v0 : 0.f);
      float v1 = acc[mt][nt][1] + bv.y; o.y = f2bf(v1 > 0.f ? v1 : 0.f);
      float v2 = acc[mt][nt][2] + bv.z; o.z = f2bf(v2 > 0.f ? v2 : 0.f);
      float v3 = acc[mt][nt][3] + bv.w; o.w = f2bf(v3 > 0.f ? v3 : 0.f);
      *(ushort4*)&h[nt * 16 + l15][Hbase] = o;
    }
  }
  __syncthreads();

  // layer 2 (transposed): D[Dout=128][node=32], K=256. Wave owns 32 Dout rows.
  f32x4 acc2[2][2];
#pragma unroll
  for (int mt = 0; mt < 2; ++mt)
#pragma unroll
    for (int nt = 0; nt < 2; ++nt) acc2[mt][nt] = (f32x4){0.f, 0.f, 0.f, 0.f};
#pragma unroll
  for (int kt = 0; kt < 8; ++kt) {
    bf8 wfr[2], xfr[2];
#pragma unroll
    for (int mt = 0; mt < 2; ++mt) {
      int Dtile = wave * 2 + mt;
      wfr[mt] = *(const bf8*)(W2p + ((size_t)(Dtile * 8 + kt) * 64 + lane) * 8);
    }
#pragma unroll
    for (int nt = 0; nt < 2; ++nt)
      xfr[nt] = *(const bf8*)&h[nt * 16 + l15][kt * 32 + l4 * 8];
#pragma unroll
    for (int mt = 0; mt < 2; ++mt)
#pragma unroll
      for (int nt = 0; nt < 2; ++nt)
        acc2[mt][nt] = __builtin_amdgcn_mfma_f32_16x16x32_bf16(wfr[mt], xfr[nt], acc2[mt][nt], 0, 0, 0);
  }
  // epilogue: bias + bf16 residual + coalesced NORMAL float4 stores
#pragma unroll
  for (int mt = 0; mt < 2; ++mt) {
    int Dbase = (wave * 2 + mt) * 16 + l4 * 4;
    float4 bv = *(const float4*)(b2 + Dbase);
#pragma unroll
    for (int nt = 0; nt < 2; ++nt) {
      int node = row0 + nt * 16 + l15;
      float4 o;
      o.x = bf2f(resid[mt][nt].x) + acc2[mt][nt][0] + bv.x;
      o.y = bf2f(resid[mt][nt].y) + acc2[mt][nt][1] + bv.y;
      o.z = bf2f(resid[mt][nt].z) + acc2[mt][nt][2] + bv.z;
      o.w = bf2f(resid[mt][nt].w) + acc2[mt][nt][3] + bv.w;
      *(float4*)(out + (size_t)node * DD + Dbase) = o;
    }
  }
}

extern "C" void kernel_launch(void* const* d_in, const int* in_sizes, int n_in,
                              void* d_out, int out_size, void* d_ws, size_t ws_size,
                              hipStream_t stream) {
  const float* nodes = (const float*)d_in[0];
  const int* senders = (const int*)d_in[1];
  const int* receivers = (const int*)d_in[2];
  const float* Wm1 = (const float*)d_in[3];
  const float* bm1 = (const float*)d_in[4];
  const float* Wm2 = (const float*)d_in[5];
  const float* bm2 = (const float*)d_in[6];
  const float* Wn1 = (const float*)d_in[7];
  const float* bn1 = (const float*)d_in[8];
  const float* Wn2 = (const float*)d_in[9];
  const float* bn2 = (const float*)d_in[10];
  float* out = (float*)d_out;

  char* ws = (char*)d_ws;
  unsigned char* Mb    = (unsigned char*)(ws);                // (NN+1)*DD = 12,800,128 B (pad to 12,800,256)
  unsigned short* Xb   = (unsigned short*)(ws + 12800256);    // 25,600,000 B
  int* cnt    = (int*)(ws + 38400256);                        // 400,000 B
  int* ebuf   = (int*)(ws + 38800256);                        // 12,800,000 B (NN*CAP*4)
  unsigned short* Wm1p = (unsigned short*)(ws + 51600256);    // 65,536 B
  unsigned short* Wm2p = (unsigned short*)(ws + 51665792);    // 65,536 B
  unsigned short* Wn1p = (unsigned short*)(ws + 51731328);    // 131,072 B
  unsigned short* Wn2p = (unsigned short*)(ws + 51862400);    // 65,536 B

  prep<<<2048, 256, 0, stream>>>(Wm1, Wm2, Wn1, Wn2, Wm1p, Wm2p, Wn1p, Wn2p,
                                 cnt, nodes, Xb, Mb, ebuf);
  msg_mlp<<<1563, 512, 0, stream>>>(Xb, Wm1p, bm1, Wm2p, bm2, Mb,
                                    senders, receivers, cnt, ebuf);
  node_fused<<<3125, 256, 0, stream>>>(Xb, Mb, ebuf, cnt,
                                       Wn1p, bn1, Wn2p, bn2, out);
}